// Round 6
// baseline (176.550 us; speedup 1.0000x reference)
//
#include <hip/hip_runtime.h>

#define NEGV -1e30f

// Problem constants (fixed by setup_inputs)
constexpr int Bn = 8, Ci = 64, Hn = 64, Wn = 64, Co = 64;

// Mapping: lane = output column (64 lanes = full row), wave = one (h, co-group)
// with COB=4 output channels. Per ci: 9 per-lane vector loads (double-buffered
// one ci ahead; VMEM in-order -> exact vmcnt waits), weights as a contiguous
// per-wave stream wT2[g][ci][36] -> the 72 floats per 2-ci iteration are ONE
// contiguous run of merged wide s_loads (vs 72 scalar s_loads in round 0 /
// 30 odd-aligned in rounds 2-4: the congested shared scalar-cache pipe is the
// bottleneck theory this round tests). Row edges cost zero: up/down row
// pointers point at a NEGV buffer. Column edges: 6 cndmasks/ci.
// Core: 36 v_add + 16 v_max3 + 4 v_max + 6 cndmask = 62 VALU per 4-co ci.
// 2048 blocks = 32 waves/CU; XCD swizzle co-locates all 16 co-group blocks of
// one (b, h-quad) on one XCD's L2.
constexpr int COB = 4;          // co per wave
constexpr int NG  = Co / COB;   // 16 co-groups
constexpr int WELEM = NG * Ci * COB * 9;   // 36864 floats of wT2
constexpr int NEGN  = 64;                  // NEGV row buffer (cols 0..63)

// ---- pre-pass: wT2[g][ci][cl*9+k] = wt[g*4+cl][ci][k]; then 64 NEGV floats ---
__global__ __launch_bounds__(256)
void wtrans_kernel(const float* __restrict__ wt, float* __restrict__ wT2) {
    int idx = blockIdx.x * 256 + threadIdx.x;
    if (idx < WELEM) {
        int t  = idx % 36;
        int cl = t / 9;
        int k  = t % 9;
        int ci = (idx / 36) % Ci;
        int g  = idx / (36 * Ci);
        wT2[idx] = wt[(((size_t)(g * COB + cl)) * Ci + ci) * 9 + k];
    } else if (idx < WELEM + NEGN) {
        wT2[idx] = NEGV;
    }
}

__device__ __forceinline__ float vmax3(float a, float b, float c) {
    float d;
    asm("v_max3_f32 %0, %1, %2, %3" : "=v"(d) : "v"(a), "v"(b), "v"(c));
    return d;
}

// 3x3 window for this lane's column: rows u/c/d, cols -1/0/+1
struct X9 { float um, uc, ur, cm, cc, cr, dm, dc, dr; };

__device__ __forceinline__ void loadX(X9& x, const float* __restrict__ pu,
                                      const float* __restrict__ pc,
                                      const float* __restrict__ pd,
                                      int cl, int lane, int cr2) {
    x.um = pu[cl]; x.uc = pu[lane]; x.ur = pu[cr2];
    x.cm = pc[cl]; x.cc = pc[lane]; x.cr = pc[cr2];
    x.dm = pd[cl]; x.dc = pd[lane]; x.dr = pd[cr2];
}

// column-edge fix: 6 cndmasks (row edges are handled by the NEGV pointer trick)
__device__ __forceinline__ void edgefix(X9& x, bool eL, bool eR) {
    x.um = eL ? NEGV : x.um;  x.cm = eL ? NEGV : x.cm;  x.dm = eL ? NEGV : x.dm;
    x.ur = eR ? NEGV : x.ur;  x.cr = eR ? NEGV : x.cr;  x.dr = eR ? NEGV : x.dr;
}

__device__ __forceinline__ void loadW(float* wv, const float* __restrict__ base) {
#pragma unroll
    for (int j = 0; j < 36; j++) wv[j] = base[j];   // uniform -> merged s_load
}

__device__ __forceinline__ void computeC(float* acc, const X9& x, const float* wv) {
#pragma unroll
    for (int c = 0; c < COB; c++) {
        const float* w = wv + c * 9;
        float t0 = x.um + w[0], t1 = x.uc + w[1], t2 = x.ur + w[2];
        float t3 = x.cm + w[3], t4 = x.cc + w[4], t5 = x.cr + w[5];
        float t6 = x.dm + w[6], t7 = x.dc + w[7], t8 = x.dr + w[8];
        float m0 = vmax3(t0, t1, t2);
        float m1 = vmax3(t3, t4, t5);
        float m2 = vmax3(t6, t7, t8);
        acc[c] = vmax3(acc[c], m0, m1);
        acc[c] = fmaxf(acc[c], m2);
    }
}

__global__ __launch_bounds__(256, 8)
void maxconv_main(const float* __restrict__ x, const float* __restrict__ wT2,
                  float* __restrict__ out) {
    const int lane = threadIdx.x & 63;
    const int wid  = __builtin_amdgcn_readfirstlane(threadIdx.x >> 6);  // 0..3

    // id bits: [0:2]=xcd, [3:6]=g, [7:10]=cq. c = xcd | cq<<3 (0..127) so all
    // 16 g-blocks of one (b, h-quad) share id%8 -> same XCD -> x rows L2-local.
    const int id  = blockIdx.x;                 // 0..2047
    const int xcd = id & 7;
    const int g   = (id >> 3) & 15;             // co-group
    const int c   = xcd | ((id >> 7) << 3);     // 0..127
    const int b   = c >> 4;
    const int h   = (c & 15) * 4 + wid;         // wave-uniform output row

    const int  cl  = lane > 0      ? lane - 1 : 0;
    const int  cr2 = lane < Wn - 1 ? lane + 1 : Wn - 1;
    const bool eL  = (lane == 0);
    const bool eR  = (lane == Wn - 1);

    const float* negbuf = wT2 + WELEM;          // 64 floats of NEGV

    // row pointers; edge rows read the NEGV buffer at zero per-iter cost
    const bool hasUp = (h > 0), hasDn = (h < Hn - 1);
    const float* pc = x + (((size_t)b * Ci) * Hn + h) * Wn;
    const float* pu = hasUp ? pc - Wn : negbuf;
    const float* pd = hasDn ? pc + Wn : negbuf;
    const int sU = hasUp ? Hn * Wn : 0;         // per-ci pointer bumps
    const int sC = Hn * Wn;
    const int sD = hasDn ? Hn * Wn : 0;

    // per-wave contiguous weight stream: 9 KB starting at g*Ci*36
    const float* wrow = wT2 + (size_t)g * Ci * 36;

    float acc[COB];
#pragma unroll
    for (int q = 0; q < COB; q++) acc[q] = NEGV;

    X9 xA, xB;
    float wvA[36], wvB[36];

    // prologue: ci=0 window in flight
    loadX(xA, pu, pc, pd, cl, lane, cr2);
    pu += sU; pc += sC; pd += sD;

#pragma unroll 1
    for (int ci = 0; ci < Ci - 2; ci += 2) {
        loadX(xB, pu, pc, pd, cl, lane, cr2);   // issue ci+1 window
        pu += sU; pc += sC; pd += sD;
        loadW(wvA, wrow);                       // weights ci, ci+1: ONE
        loadW(wvB, wrow + 36);                  //   contiguous 72-float run
        wrow += 72;
        __builtin_amdgcn_sched_barrier(0);      // pin issues before compute
        edgefix(xA, eL, eR);
        computeC(acc, xA, wvA);                 // ci   (covers xB + wvB latency)
        loadX(xA, pu, pc, pd, cl, lane, cr2);   // issue ci+2 window
        pu += sU; pc += sC; pd += sD;
        __builtin_amdgcn_sched_barrier(0);
        edgefix(xB, eL, eR);
        computeC(acc, xB, wvB);                 // ci+1
    }
    // tail: ci = 62 (in xA), 63
    loadX(xB, pu, pc, pd, cl, lane, cr2);
    loadW(wvA, wrow);
    loadW(wvB, wrow + 36);
    edgefix(xA, eL, eR);
    computeC(acc, xA, wvA);
    edgefix(xB, eL, eR);
    computeC(acc, xB, wvB);

    // stores: 4 co planes, coalesced across lanes
    float* po = out + (((size_t)b * Co + g * COB) * Hn + h) * Wn + lane;
#pragma unroll
    for (int q = 0; q < COB; q++) po[(size_t)q * Hn * Wn] = acc[q];
}

extern "C" void kernel_launch(void* const* d_in, const int* in_sizes, int n_in,
                              void* d_out, int out_size, void* d_ws, size_t ws_size,
                              hipStream_t stream) {
    const float* x  = (const float*)d_in[0];
    const float* wt = (const float*)d_in[1];
    float* out = (float*)d_out;
    float* wT2 = (float*)d_ws;   // 36864 + 64 floats = 147712 B

    wtrans_kernel<<<(WELEM + NEGN + 255) / 256, 256, 0, stream>>>(wt, wT2);

    // 2048 blocks = 8 blocks/CU = 32 waves/CU (8 waves/SIMD)
    maxconv_main<<<2048, 256, 0, stream>>>(x, wT2, out);
}

// Round 7
// 126.469 us; speedup vs baseline: 1.3960x; 1.3960x over previous
//
#include <hip/hip_runtime.h>

#define NEGV -1e30f

// Problem constants (fixed by setup_inputs)
constexpr int Bn = 8, Ci = 64, Hn = 64, Wn = 64, Co = 64;

// R0 geometry (proven 71 us), scalar path eliminated:
//   lane = output column (64 lanes = row), wave = one output row, block = 4
//   rows x COB=8 output channels. Weights staged ONCE per block into LDS
//   (24 KB, padded [ci][cl][12] so per-co reads are ds_read_b128-aligned
//   broadcasts). Hot loop has ZERO s_loads: x via 9 per-lane VMEM loads/ci
//   (SGPR base bumped by SALU + imm row offsets -> ~no address VALU),
//   double-buffered one ci ahead; weights via uniform-address ds_read_b128
//   (broadcast, conflict-free). Theory: all prior rounds (64-71 us) were
//   choked by ~32 MB streamed through the scalar cache; VALUBusy is inflated
//   ~2x by the gfx94x formula (SIMD-16 assumption), real VALU ~40%.
// Grid 1024 blocks, swizzled so all 8 co-groups of one (b,h-quad) share an
// XCD (id%8 = hq%8) -> x rows L2-local, no cross-XCD refetch.
constexpr int COB = 8;   // co per block
constexpr int HT  = 4;   // rows per block (one per wave)

__device__ __forceinline__ float vmax3(float a, float b, float c) {
    float d;
    asm("v_max3_f32 %0, %1, %2, %3" : "=v"(d) : "v"(a), "v"(b), "v"(c));
    return d;
}

// 3x3 window for this lane's column: rows u/c/d, cols -1/0/+1
struct X9 { float um, uc, ur, cm, cc, cr, dm, dc, dr; };

__device__ __forceinline__ void loadX(X9& v, const float* __restrict__ p,
                                      int cl, int lane, int cr,
                                      bool hasUp, bool hasDn) {
    v.cm = p[cl]; v.cc = p[lane]; v.cr = p[cr];
    if (hasUp) { v.um = p[cl - Wn]; v.uc = p[lane - Wn]; v.ur = p[cr - Wn]; }
    else       { v.um = NEGV;      v.uc = NEGV;          v.ur = NEGV; }
    if (hasDn) { v.dm = p[cl + Wn]; v.dc = p[lane + Wn]; v.dr = p[cr + Wn]; }
    else       { v.dm = NEGV;      v.dc = NEGV;          v.dr = NEGV; }
}

// column-edge fix: 6 cndmasks per ci (row edges are uniform branches above)
__device__ __forceinline__ void edgefix(X9& v, bool eL, bool eR) {
    v.um = eL ? NEGV : v.um; v.cm = eL ? NEGV : v.cm; v.dm = eL ? NEGV : v.dm;
    v.ur = eR ? NEGV : v.ur; v.cr = eR ? NEGV : v.cr; v.dr = eR ? NEGV : v.dr;
}

// per-co weights from LDS as aligned broadcast reads: 2x b128 + 1x b32
__device__ __forceinline__ void computeC(float* acc, const X9& v,
                                         const float* __restrict__ lwp) {
#pragma unroll
    for (int c = 0; c < COB; c++) {
        const float4 wa = *reinterpret_cast<const float4*>(lwp + c * 12);
        const float4 wb = *reinterpret_cast<const float4*>(lwp + c * 12 + 4);
        const float  w8 = lwp[c * 12 + 8];
        float t0 = v.um + wa.x, t1 = v.uc + wa.y, t2 = v.ur + wa.z;
        float t3 = v.cm + wa.w, t4 = v.cc + wb.x, t5 = v.cr + wb.y;
        float t6 = v.dm + wb.z, t7 = v.dc + wb.w, t8 = v.dr + w8;
        float m0 = vmax3(t0, t1, t2);
        float m1 = vmax3(t3, t4, t5);
        float m2 = vmax3(t6, t7, t8);
        acc[c] = vmax3(acc[c], m0, m1);
        acc[c] = fmaxf(acc[c], m2);
    }
}

__global__ __launch_bounds__(256, 4)
void maxconv_main(const float* __restrict__ x, const float* __restrict__ wt,
                  float* __restrict__ out) {
    // [ci][cl][12] padded so each co's 9 weights start 16B-aligned
    __shared__ __align__(16) float lw[Ci * COB * 12];   // 24576 B

    const int tid  = threadIdx.x;
    const int lane = tid & 63;
    const int wrow = tid >> 6;                 // 0..3

    // id = g*128 + (b*16 + hq): id%8 = hq%8 -> all 8 g-blocks of one
    // (b,hq) land on the same XCD; hq spreads across XCDs for balance.
    const int id = blockIdx.x;                 // 0..1023
    const int g  = id >> 7;                    // co-group 0..7
    const int c  = id & 127;
    const int b  = c >> 4;
    const int hq = c & 15;
    const int h  = hq * HT + wrow;             // wave-uniform output row
    const int co0 = g * COB;

    // ---- stage weights once: wt[co0..co0+7][*][*] -> lw[ci][cl][12] ----
    const float* wg = wt + (size_t)co0 * Ci * 9;
    for (int t = tid; t < Ci * COB * 9; t += 256) {
        int cl  = t / (Ci * 9);
        int rem = t - cl * (Ci * 9);
        int ci  = rem / 9;
        int k   = rem - ci * 9;
        lw[(ci * COB + cl) * 12 + k] = wg[t];
    }
    __syncthreads();

    const int  cl = lane > 0      ? lane - 1 : 0;
    const int  cr = lane < Wn - 1 ? lane + 1 : Wn - 1;
    const bool eL = (lane == 0);
    const bool eR = (lane == Wn - 1);
    const bool hasUp = (h > 0);        // wave-uniform
    const bool hasDn = (h < Hn - 1);

    const float* p = x + ((size_t)b * Ci * Hn + h) * Wn;

    float acc[COB];
#pragma unroll
    for (int q = 0; q < COB; q++) acc[q] = NEGV;

    X9 xA, xB;

    // prologue: ci=0 window in flight
    loadX(xA, p, cl, lane, cr, hasUp, hasDn);  p += Hn * Wn;

#pragma unroll 1
    for (int ci = 0; ci < Ci - 2; ci += 2) {
        loadX(xB, p, cl, lane, cr, hasUp, hasDn);  p += Hn * Wn;  // ci+1
        edgefix(xA, eL, eR);
        computeC(acc, xA, lw + ci * (COB * 12));                  // ci
        loadX(xA, p, cl, lane, cr, hasUp, hasDn);  p += Hn * Wn;  // ci+2
        edgefix(xB, eL, eR);
        computeC(acc, xB, lw + (ci + 1) * (COB * 12));            // ci+1
    }
    // tail: ci = 62 (in xA), 63
    loadX(xB, p, cl, lane, cr, hasUp, hasDn);
    edgefix(xA, eL, eR);
    computeC(acc, xA, lw + 62 * (COB * 12));
    edgefix(xB, eL, eR);
    computeC(acc, xB, lw + 63 * (COB * 12));

    // store 8 co planes, fully coalesced (lane = col) — clean 8 MB writes
    float* po = out + (((size_t)b * Co + co0) * Hn + h) * Wn + lane;
#pragma unroll
    for (int q = 0; q < COB; q++) po[(size_t)q * Hn * Wn] = acc[q];
}

extern "C" void kernel_launch(void* const* d_in, const int* in_sizes, int n_in,
                              void* d_out, int out_size, void* d_ws, size_t ws_size,
                              hipStream_t stream) {
    const float* x  = (const float*)d_in[0];
    const float* wt = (const float*)d_in[1];
    float* out = (float*)d_out;

    // single dispatch, no pre-pass: weights staged from original layout
    maxconv_main<<<1024, 256, 0, stream>>>(x, wt, out);
}

// Round 8
// 114.781 us; speedup vs baseline: 1.5381x; 1.1018x over previous
//
#include <hip/hip_runtime.h>

#define NEGV -1e30f

// Problem constants (fixed by setup_inputs)
constexpr int Bn = 8, Ci = 64, Hn = 64, Wn = 64, Co = 64;
constexpr int WT_ELEMS = Ci * 9 * Co;   // 36864

// ---- pre-pass: wT[ci][k][co] = wt[co][ci][k] (147456 B in d_ws) ----
__global__ __launch_bounds__(256)
void wtrans_kernel(const float* __restrict__ wt, float* __restrict__ wT) {
    int idx = blockIdx.x * 256 + threadIdx.x;
    if (idx < WT_ELEMS) {
        int co = idx & 63;
        int k  = (idx >> 6) % 9;
        int ci = idx / 576;
        wT[idx] = wt[((size_t)co * Ci + ci) * 9 + k];
    }
}

__device__ __forceinline__ float vmax3(float a, float b, float c) {
    float d;
    asm("v_max3_f32 %0, %1, %2, %3" : "=v"(d) : "v"(a), "v"(b), "v"(c));
    return d;
}

// uniform LDS window read: 10 floats = b128 + b128 + b64 (16B-aligned base)
__device__ __forceinline__ void read10(float* o, const float* __restrict__ p) {
    float4 a = *reinterpret_cast<const float4*>(p);
    float4 b = *reinterpret_cast<const float4*>(p + 4);
    float2 c = *reinterpret_cast<const float2*>(p + 8);
    o[0] = a.x; o[1] = a.y; o[2] = a.z; o[3] = a.w;
    o[4] = b.x; o[5] = b.y; o[6] = b.z; o[7] = b.w;
    o[8] = c.x; o[9] = c.y;
}

// pure core: per px 9 v_add + 4 v_max3 + 1 v_max
__device__ __forceinline__ void compute8(float* acc, const float* xu,
                                         const float* xc, const float* xd,
                                         const float* wv) {
#pragma unroll
    for (int j = 0; j < 8; j++) {
        float t0 = xu[j] + wv[0], t1 = xu[j + 1] + wv[1], t2 = xu[j + 2] + wv[2];
        float t3 = xc[j] + wv[3], t4 = xc[j + 1] + wv[4], t5 = xc[j + 2] + wv[5];
        float t6 = xd[j] + wv[6], t7 = xd[j + 1] + wv[7], t8 = xd[j + 2] + wv[8];
        float m0 = vmax3(t0, t1, t2);
        float m1 = vmax3(t3, t4, t5);
        float m2 = vmax3(t6, t7, t8);
        acc[j] = vmax3(acc[j], m0, m1);
        acc[j] = fmaxf(acc[j], m2);
    }
}

// Clean-pipes kernel: lane = co (64 lanes = all output channels); wave = 8 px
// of one output row; block = (b, h, half-row of 32 px) = 4 waves. The block's
// entire x working set (3 rows x 34 cols x 64 ci, edges pre-NEGV'd) is staged
// into LDS ONCE -> main loop has NO barriers, NO edge masking, NO per-lane
// addressing: per ci just 9 coalesced weight VMEM (SGPR base + imm k*256) +
// 9 uniform broadcast ds_reads + 112 core VALU.
__global__ __launch_bounds__(256, 4)
void maxconv_main(const float* __restrict__ x, const float* __restrict__ wT,
                  float* __restrict__ out) {
    __shared__ __align__(16) float xs[Ci * 120];   // [ci][3 rows][40] = 30720 B

    const int tid  = threadIdx.x;
    const int lane = tid & 63;
    const int wvid = tid >> 6;                      // 0..3

    // XCD chunking: hw id%8 selects XCD; give XCD k the logical chunk
    // [k*128, (k+1)*128) = exactly one batch image b (4.2 MB x, ~L2-resident).
    const int lg   = ((blockIdx.x & 7) << 7) | (blockIdx.x >> 3);
    const int b    = lg >> 7;
    const int rem  = lg & 127;
    const int h    = rem >> 1;
    const int half = rem & 1;
    const int w0h  = half << 5;                     // 0 or 32

    // ---- upfront staging: threads {0..101} do ci 0..31, {128..229} ci 32..63.
    // Each stage thread owns one (row r, slot s); invalid coords write NEGV
    // (covers row/col borders for free — no masking in the main loop).
    {
        const int st     = (tid < 128) ? tid : tid - 128;
        const int cibase = (tid < 128) ? 0 : 32;
        if (st < 102) {
            const int r    = st / 34;
            const int s    = st - r * 34;
            const int grow = h - 1 + r;
            const int gcol = w0h - 1 + s;
            const bool valid = (grow >= 0) && (grow < Hn) && (gcol >= 0) && (gcol < Wn);
            const int cg   = valid ? grow : 0;
            const int cc   = valid ? gcol : 0;
            const float* gp = x + (((size_t)b * Ci + cibase) * Hn + cg) * Wn + cc;
            const int dst  = r * 40 + s;
#pragma unroll 1
            for (int c8 = 0; c8 < 32; c8 += 8) {
                float v[8];
#pragma unroll
                for (int i = 0; i < 8; i++)
                    v[i] = valid ? gp[(size_t)(c8 + i) * Hn * Wn] : NEGV;
#pragma unroll
                for (int i = 0; i < 8; i++)
                    xs[(cibase + c8 + i) * 120 + dst] = v[i];
            }
        }
    }
    __syncthreads();   // the only block-wide sync

    const int woff = wvid * 8;   // this wave's slot base (16B-aligned reads)

    float acc[8];
#pragma unroll
    for (int j = 0; j < 8; j++) acc[j] = NEGV;

#pragma unroll 1
    for (int ci = 0; ci < Ci; ci += 2) {
        // ---- ci ----
        const float* wrow = wT + ci * 576;          // uniform SGPR base
        float wv[9];
#pragma unroll
        for (int k = 0; k < 9; k++) wv[k] = wrow[k * 64 + lane];
        float xu[10], xc[10], xd[10];
        const float* base0 = xs + ci * 120 + woff;
        read10(xu, base0); read10(xc, base0 + 40); read10(xd, base0 + 80);
        compute8(acc, xu, xc, xd, wv);

        // ---- ci+1 ----
        const float* wrow2 = wrow + 576;
        float wv2[9];
#pragma unroll
        for (int k = 0; k < 9; k++) wv2[k] = wrow2[k * 64 + lane];
        const float* base1 = base0 + 120;
        read10(xu, base1); read10(xc, base1 + 40); read10(xd, base1 + 80);
        compute8(acc, xu, xc, xd, wv2);
    }

    // lane holds 8 consecutive px of its co plane -> two dwordx4 stores
    float* po = out + (((size_t)b * Co + lane) * Hn + h) * Wn + w0h + woff;
    *reinterpret_cast<float4*>(po)     = make_float4(acc[0], acc[1], acc[2], acc[3]);
    *reinterpret_cast<float4*>(po + 4) = make_float4(acc[4], acc[5], acc[6], acc[7]);
}

extern "C" void kernel_launch(void* const* d_in, const int* in_sizes, int n_in,
                              void* d_out, int out_size, void* d_ws, size_t ws_size,
                              hipStream_t stream) {
    const float* x  = (const float*)d_in[0];
    const float* wt = (const float*)d_in[1];
    float* out = (float*)d_out;
    float* wT  = (float*)d_ws;   // 147456 B

    wtrans_kernel<<<(WT_ELEMS + 255) / 256, 256, 0, stream>>>(wt, wT);

    // 1024 blocks = 4 blocks/CU = 16 waves/CU; LDS 30 KB x 4 = 120 KB/CU
    maxconv_main<<<1024, 256, 0, stream>>>(x, wT, out);
}